// Round 12
// baseline (401.119 us; speedup 1.0000x reference)
//
#include <hip/hip_runtime.h>
#include <hip/hip_bf16.h>

#define BB 32
#define NN 512
#define MM 512
#define DD 1024

typedef __attribute__((ext_vector_type(8))) short short8;
typedef __attribute__((ext_vector_type(8))) unsigned short ushort8v;
typedef __attribute__((ext_vector_type(4))) float f32x4;

#define ASYNC_COPY16(g, l) \
    __builtin_amdgcn_global_load_lds((__attribute__((address_space(1))) void*)(g), \
                                     (__attribute__((address_space(3))) void*)(l), 16, 0, 0)

__device__ inline unsigned short f2bf(float f) {
    unsigned int u = __float_as_uint(f);
    u += 0x7fffu + ((u >> 16) & 1u);
    return (unsigned short)(u >> 16);
}

#define SPLIT1(vv, hh, ll) { unsigned short h_ = f2bf(vv); \
    float hf_ = __uint_as_float((unsigned int)h_ << 16); \
    hh = h_; ll = f2bf((vv) - hf_); }

__device__ inline void split8(float4 a0, float4 a1, ushort8v& h, ushort8v& l) {
    SPLIT1(a0.x, h[0], l[0]) SPLIT1(a0.y, h[1], l[1])
    SPLIT1(a0.z, h[2], l[2]) SPLIT1(a0.w, h[3], l[3])
    SPLIT1(a1.x, h[4], l[4]) SPLIT1(a1.y, h[5], l[5])
    SPLIT1(a1.z, h[6], l[6]) SPLIT1(a1.w, h[7], l[7])
}

// ---------------------------------------------------------------------------
// K0: streaming split-convert, MLP-restructured. Per thread-iteration:
// 4 independent float4 loads (64B in flight), split, 4 x 16B nontemporal
// stores (ushort8 = coalescing sweet spot). Grid 2048 x 4-iter unrolled
// grid-stride: compiler overlaps iter i+1 loads with iter i stores.
// NT stores skip L2 allocation (outputs consumed next-kernel from HBM).
// ---------------------------------------------------------------------------
__global__ __launch_bounds__(256) void convert_split(
    const float* __restrict__ x1, const float* __restrict__ x2,
    unsigned short* __restrict__ x1h, unsigned short* __restrict__ x1l,
    unsigned short* __restrict__ x2h, unsigned short* __restrict__ x2l) {
    int tid = blockIdx.x * 256 + threadIdx.x;            // 0..524287
#pragma unroll
    for (int it = 0; it < 4; ++it) {
        size_t c = (size_t)tid + (size_t)it * 524288;    // ushort8 chunk, < 2097152
        const float4* p1 = (const float4*)x1 + 2 * c;
        const float4* p2 = (const float4*)x2 + 2 * c;
        float4 a0 = p1[0];
        float4 a1 = p1[1];
        float4 b0 = p2[0];
        float4 b1 = p2[1];
        ushort8v h1, l1, h2, l2;
        split8(a0, a1, h1, l1);
        split8(b0, b1, h2, l2);
        __builtin_nontemporal_store(h1, (ushort8v*)x1h + c);
        __builtin_nontemporal_store(l1, (ushort8v*)x1l + c);
        __builtin_nontemporal_store(h2, (ushort8v*)x2h + c);
        __builtin_nontemporal_store(l2, (ushort8v*)x2l + c);
    }
}

// ---------------------------------------------------------------------------
// K1: align GEMM + fused partial softmax stats. T4 counted-vmcnt K-loop
// (unchanged, R11-passing).
// ---------------------------------------------------------------------------
__global__ __launch_bounds__(512, 4) void gemm_align(
    const unsigned short* __restrict__ x1h, const unsigned short* __restrict__ x1l,
    const unsigned short* __restrict__ x2h, const unsigned short* __restrict__ x2l,
    const int* __restrict__ mask1, const int* __restrict__ mask2,
    float* __restrict__ alg,
    float* __restrict__ rp_max, float* __restrict__ rp_sum,
    float* __restrict__ cp_max, float* __restrict__ cp_sum) {
    __shared__ unsigned short S[2][16384];
    int bid = blockIdx.x;
    int nb = (bid & 7) * 64 + (bid >> 3);    // XCD batch-affinity swizzle
    int b = nb >> 4; int tl = nb & 15;
    int nt = tl >> 2, mt = tl & 3;
    int n0 = nt * 128, m0 = mt * 128;
    int t = threadIdx.x; int w = t >> 6; int l = t & 63;
    int lane16 = l & 15, q = l >> 4, q8 = q * 8;
    int wr = (w >> 2) * 64;
    int wc = (w & 3) * 32;
    f32x4 acc[4][2];
#pragma unroll
    for (int i = 0; i < 4; ++i)
#pragma unroll
        for (int j = 0; j < 2; ++j) acc[i][j] = (f32x4){0.f, 0.f, 0.f, 0.f};
    const unsigned short* gs[4];
    int ls[4];
#pragma unroll
    for (int s = 0; s < 4; ++s) {
        int qq = w * 4 + s;
        int row0 = (qq & 7) * 16;
        const unsigned short* base; int lb;
        if (qq < 8)       { base = x1h + ((size_t)b * 512 + n0) * 1024; lb = 0; }
        else if (qq < 16) { base = x1l + ((size_t)b * 512 + n0) * 1024; lb = 4096; }
        else if (qq < 24) { base = x2h + ((size_t)b * 512 + m0) * 1024; lb = 8192; }
        else              { base = x2l + ((size_t)b * 512 + m0) * 1024; lb = 12288; }
        gs[s] = base + (size_t)(row0 + (l >> 2)) * 1024 + (l & 3) * 8;
        ls[s] = lb + row0 * 32 + l * 8;
    }
#pragma unroll
    for (int s = 0; s < 4; ++s)
        ASYNC_COPY16(gs[s], &S[0][ls[s]]);
    int cur = 0;
    for (int kk = 0; kk < 1024; kk += 32) {
        if (kk + 32 < 1024) {
#pragma unroll
            for (int s = 0; s < 4; ++s)
                ASYNC_COPY16(gs[s] + kk + 32, &S[cur ^ 1][ls[s]]);
            __builtin_amdgcn_sched_barrier(0);
            asm volatile("s_waitcnt vmcnt(4)" ::: "memory");   // tile-t landed, t+1 in flight
        } else {
            asm volatile("s_waitcnt vmcnt(0)" ::: "memory");   // final tile
        }
        __builtin_amdgcn_s_barrier();
        __builtin_amdgcn_sched_barrier(0);
        const unsigned short* Sb = S[cur];
        short8 ah[4], al[4], bh[2], bl[2];
#pragma unroll
        for (int i = 0; i < 4; ++i) {
            int off = (wr + i * 16 + lane16) * 32 + q8;
            ah[i] = *(const short8*)&Sb[off];
            al[i] = *(const short8*)&Sb[4096 + off];
        }
#pragma unroll
        for (int j = 0; j < 2; ++j) {
            int off = (wc + j * 16 + lane16) * 32 + q8;
            bh[j] = *(const short8*)&Sb[8192 + off];
            bl[j] = *(const short8*)&Sb[12288 + off];
        }
#pragma unroll
        for (int i = 0; i < 4; ++i)
#pragma unroll
            for (int j = 0; j < 2; ++j) {
                acc[i][j] = __builtin_amdgcn_mfma_f32_16x16x32_bf16(ah[i], bh[j], acc[i][j], 0, 0, 0);
                acc[i][j] = __builtin_amdgcn_mfma_f32_16x16x32_bf16(ah[i], bl[j], acc[i][j], 0, 0, 0);
                acc[i][j] = __builtin_amdgcn_mfma_f32_16x16x32_bf16(al[i], bh[j], acc[i][j], 0, 0, 0);
            }
        __builtin_amdgcn_sched_barrier(0);
        __builtin_amdgcn_s_barrier();   // all waves done reading buf[cur] before overwrite
        cur ^= 1;
    }
    float* ob = alg + ((size_t)b * 512 + n0 + wr) * 512 + m0 + wc;
    int q4 = q * 4;
#pragma unroll
    for (int i = 0; i < 4; ++i)
#pragma unroll
        for (int j = 0; j < 2; ++j)
#pragma unroll
            for (int r = 0; r < 4; ++r)
                ob[(size_t)(i * 16 + q4 + r) * 512 + j * 16 + lane16] = acc[i][j][r];
    int mk2[2];
#pragma unroll
    for (int j = 0; j < 2; ++j) mk2[j] = mask2[b * 512 + m0 + wc + j * 16 + lane16];
    int mk1r[4][4];
#pragma unroll
    for (int i = 0; i < 4; ++i)
#pragma unroll
        for (int r = 0; r < 4; ++r) mk1r[i][r] = mask1[b * 512 + n0 + wr + i * 16 + q4 + r];
#pragma unroll
    for (int j = 0; j < 2; ++j) {
        float cm = -3.0e38f;
#pragma unroll
        for (int i = 0; i < 4; ++i)
#pragma unroll
            for (int r = 0; r < 4; ++r)
                if (mk1r[i][r]) cm = fmaxf(cm, acc[i][j][r]);
        cm = fmaxf(cm, __shfl_xor(cm, 16));
        cm = fmaxf(cm, __shfl_xor(cm, 32));
        float cs = 0.f;
#pragma unroll
        for (int i = 0; i < 4; ++i)
#pragma unroll
            for (int r = 0; r < 4; ++r)
                cs += mk1r[i][r] ? __expf(acc[i][j][r] - cm) : 0.f;
        cs += __shfl_xor(cs, 16);
        cs += __shfl_xor(cs, 32);
        if (q == 0) {
            size_t o = ((size_t)b * 8 + nt * 2 + (w >> 2)) * 512 + m0 + wc + j * 16 + lane16;
            cp_max[o] = cm;
            cp_sum[o] = cs;
        }
    }
    float* rmS = (float*)&S[0][0];
    float* rsS = rmS + 512;
#pragma unroll
    for (int i = 0; i < 4; ++i)
#pragma unroll
        for (int r = 0; r < 4; ++r) {
            float v0 = acc[i][0][r], v1 = acc[i][1][r];
            float rm = fmaxf(mk2[0] ? v0 : -3.0e38f, mk2[1] ? v1 : -3.0e38f);
            rm = fmaxf(rm, __shfl_xor(rm, 1));
            rm = fmaxf(rm, __shfl_xor(rm, 2));
            rm = fmaxf(rm, __shfl_xor(rm, 4));
            rm = fmaxf(rm, __shfl_xor(rm, 8));
            float rs = (mk2[0] ? __expf(v0 - rm) : 0.f) + (mk2[1] ? __expf(v1 - rm) : 0.f);
            rs += __shfl_xor(rs, 1);
            rs += __shfl_xor(rs, 2);
            rs += __shfl_xor(rs, 4);
            rs += __shfl_xor(rs, 8);
            if (lane16 == 0) {
                int row = i * 16 + q4 + r;
                rmS[w * 64 + row] = rm;
                rsS[w * 64 + row] = rs;
            }
        }
    __syncthreads();
    if (t < 128) {
        int grp = t >> 6, rloc = t & 63;
        float M = -3.0e38f;
#pragma unroll
        for (int ww = 0; ww < 4; ++ww) M = fmaxf(M, rmS[(grp * 4 + ww) * 64 + rloc]);
        float Ssum = 0.f;
#pragma unroll
        for (int ww = 0; ww < 4; ++ww)
            Ssum += rsS[(grp * 4 + ww) * 64 + rloc] * __expf(rmS[(grp * 4 + ww) * 64 + rloc] - M);
        size_t o = ((size_t)b * 4 + mt) * 512 + n0 + t;
        rp_max[o] = M;
        rp_sum[o] = Ssum;
    }
}

// ---------------------------------------------------------------------------
// K3': apply softmax with combine_stats fused (unchanged, R11-passing).
// ---------------------------------------------------------------------------
__global__ __launch_bounds__(256) void apply_softmax(
    const float* __restrict__ alg, const int* __restrict__ mask1,
    const int* __restrict__ mask2,
    const float* __restrict__ rp_max, const float* __restrict__ rp_sum,
    const float* __restrict__ cp_max, const float* __restrict__ cp_sum,
    unsigned short* __restrict__ attn12, unsigned short* __restrict__ attn21) {
    int bid = blockIdx.x; int b = bid >> 6; int rem = bid & 63;
    int m0 = (rem >> 3) * 64, n0 = (rem & 7) * 64;
    int t = threadIdx.x;
    __shared__ float lds[64 * 65];
    __shared__ float st[4][64];   // rowmax, rowinv, colmax, colinv (block-local)
    if (t < 64) {
        int n = n0 + t;
        float M = -3.0e38f;
#pragma unroll
        for (int tt = 0; tt < 4; ++tt) M = fmaxf(M, rp_max[((size_t)b * 4 + tt) * 512 + n]);
        float Ssum = 0.f;
#pragma unroll
        for (int tt = 0; tt < 4; ++tt) {
            size_t o = ((size_t)b * 4 + tt) * 512 + n;
            Ssum += rp_sum[o] * __expf(rp_max[o] - M);
        }
        st[0][t] = M; st[1][t] = 1.0f / Ssum;
    } else if (t < 128) {
        int m = m0 + (t - 64);
        float M = -3.0e38f;
#pragma unroll
        for (int tt = 0; tt < 8; ++tt) M = fmaxf(M, cp_max[((size_t)b * 8 + tt) * 512 + m]);
        float Ssum = 0.f;
#pragma unroll
        for (int tt = 0; tt < 8; ++tt) {
            size_t o = ((size_t)b * 8 + tt) * 512 + m;
            Ssum += cp_sum[o] * __expf(cp_max[o] - M);
        }
        st[2][t - 64] = M; st[3][t - 64] = 1.0f / Ssum;
    }
    __syncthreads();
    int jj = t & 63; int ii = t >> 6;
    int mk2 = mask2[b * 512 + m0 + jj];
    unsigned short e12[16];
#pragma unroll
    for (int p = 0; p < 16; ++p) {
        int n = ii + p * 4;
        float v = alg[((size_t)b * 512 + n0 + n) * 512 + m0 + jj];
        lds[n * 65 + jj] = v;
        e12[p] = mk2 ? f2bf(__expf(v - st[0][n]) * st[1][n]) : (unsigned short)0;
    }
    __syncthreads();
#pragma unroll
    for (int p = 0; p < 16; ++p) {
        int n = ii + p * 4;
        attn12[((size_t)b * 512 + n0 + n) * 512 + m0 + jj] = e12[p];
    }
    int mk1 = mask1[b * 512 + n0 + jj];
#pragma unroll
    for (int p = 0; p < 16; ++p) {
        int mm = ii + p * 4;
        float v = lds[jj * 65 + mm];
        unsigned short pv = mk1 ? f2bf(__expf(v - st[2][mm]) * st[3][mm]) : (unsigned short)0;
        attn21[((size_t)b * 512 + m0 + mm) * 512 + n0 + jj] = pv;
    }
}

// ---------------------------------------------------------------------------
// K4: merged PV GEMM, T4 counted-vmcnt loop (unchanged, R11-passing).
// ---------------------------------------------------------------------------
__global__ __launch_bounds__(256) void gemm_pv2(
    const unsigned short* __restrict__ attn12, const unsigned short* __restrict__ x2h,
    const unsigned short* __restrict__ attn21, const unsigned short* __restrict__ x1h,
    float* __restrict__ out1, float* __restrict__ out2) {
    __shared__ unsigned short SA[2][4096];       // [128n][32m] bf16
    __shared__ unsigned int   SB[2][32 * 65];    // [32m][130 u16] padded
    int bid0 = blockIdx.x;
    const unsigned short* P; const unsigned short* V; float* out;
    if (bid0 < 1024) { P = attn12; V = x2h; out = out1; }
    else             { P = attn21; V = x1h; out = out2; }
    int bid = bid0 & 1023;
    int nb = (bid & 7) * 128 + (bid >> 3);  // XCD batch-affinity swizzle
    int b = nb >> 5; int rem = nb & 31;
    int n0 = (rem >> 3) * 128, d0 = (rem & 7) * 128;
    int t = threadIdx.x; int w = t >> 6; int l = t & 63;
    int lane16 = l & 15, q = l >> 4, q8 = q * 8;
    int wr = (w >> 1) * 64, wc = (w & 1) * 64;
    f32x4 acc[4][4];
#pragma unroll
    for (int i = 0; i < 4; ++i)
#pragma unroll
        for (int j = 0; j < 4; ++j) acc[i][j] = (f32x4){0.f, 0.f, 0.f, 0.f};
    const unsigned short* gA = P + ((size_t)b * 512 + n0) * 512;
    const unsigned short* gsA[2];
    int ldsa[2];
#pragma unroll
    for (int s = 0; s < 2; ++s) {
        int a = w * 2 + s;
        gsA[s] = gA + (size_t)(a * 16 + (l >> 2)) * 512 + (l & 3) * 8;
        ldsa[s] = a * 512 + l * 8;
    }
    int dch = l & 15;
    int mloc[2]; mloc[0] = w * 4 + q; mloc[1] = mloc[0] + 16;
    const unsigned short* gB0[2];
#pragma unroll
    for (int s = 0; s < 2; ++s)
        gB0[s] = V + (size_t)b * 524288 + (size_t)mloc[s] * 1024 + d0 + dch * 8;
    union U8 { short8 s; unsigned int u[4]; };
    U8 bv[2];
#pragma unroll
    for (int s = 0; s < 2; ++s) bv[s].s = *(const short8*)gB0[s];
#pragma unroll
    for (int s = 0; s < 2; ++s)
        ASYNC_COPY16(gsA[s], &SA[0][ldsa[s]]);
#pragma unroll
    for (int s = 0; s < 2; ++s)
#pragma unroll
        for (int c = 0; c < 4; ++c)
            SB[0][mloc[s] * 65 + dch * 4 + c] = bv[s].u[c];
    __syncthreads();
    int cur = 0;
    for (int kk = 0; kk < 512; kk += 32) {
        int more = (kk + 32 < 512);
        if (more) {
#pragma unroll
            for (int s = 0; s < 2; ++s) bv[s].s = *(const short8*)(gB0[s] + (size_t)(kk + 32) * 1024);
            __builtin_amdgcn_sched_barrier(0);   // keep bv-loads older than A-DMA
#pragma unroll
            for (int s = 0; s < 2; ++s)
                ASYNC_COPY16(gsA[s] + kk + 32, &SA[cur ^ 1][ldsa[s]]);
            __builtin_amdgcn_sched_barrier(0);
            asm volatile("s_waitcnt vmcnt(4)" ::: "memory");   // A(t) landed; {bv,A}(t+1) in flight
        } else {
            asm volatile("s_waitcnt vmcnt(0)" ::: "memory");
        }
        __builtin_amdgcn_s_barrier();
        __builtin_amdgcn_sched_barrier(0);
        short8 af[4];
#pragma unroll
        for (int i = 0; i < 4; ++i)
            af[i] = *(const short8*)&SA[cur][(wr + i * 16 + lane16) * 32 + q8];
        const unsigned short* Bs = (const unsigned short*)SB[cur];
        short8 bf[4];
#pragma unroll
        for (int j = 0; j < 4; ++j) {
            int col = wc + j * 16 + lane16;
#pragma unroll
            for (int e = 0; e < 8; ++e)
                bf[j][e] = (short)Bs[(q8 + e) * 130 + col];
        }
#pragma unroll
        for (int i = 0; i < 4; ++i)
#pragma unroll
            for (int j = 0; j < 4; ++j)
                acc[i][j] = __builtin_amdgcn_mfma_f32_16x16x32_bf16(af[i], bf[j], acc[i][j], 0, 0, 0);
        if (more) {
#pragma unroll
            for (int s = 0; s < 2; ++s)
#pragma unroll
                for (int c = 0; c < 4; ++c)
                    SB[cur ^ 1][mloc[s] * 65 + dch * 4 + c] = bv[s].u[c];
        }
        asm volatile("s_waitcnt lgkmcnt(0)" ::: "memory");   // SB writes visible
        __builtin_amdgcn_sched_barrier(0);
        __builtin_amdgcn_s_barrier();
        cur ^= 1;
    }
    int q4 = q * 4;
#pragma unroll
    for (int i = 0; i < 4; ++i)
#pragma unroll
        for (int j = 0; j < 4; ++j)
#pragma unroll
            for (int r = 0; r < 4; ++r) {
                int rr = n0 + wr + i * 16 + q4 + r;
                int dd = d0 + wc + j * 16 + lane16;
                out[((size_t)b * 512 + rr) * DD + dd] = acc[i][j][r];
            }
}

// ---------------------------------------------------------------------------
// ws layout (224MB): x1h 0 | x2h 32M | x1l 128M | x2l 160M | alg 192M.
// attn12 @128M (reuses x1l), attn21 @160M (reuses x2l). Partial stats in
// d_out scratch (dead before gemm_pv2 writes it). 4 launches total.
// ---------------------------------------------------------------------------
extern "C" void kernel_launch(void* const* d_in, const int* in_sizes, int n_in,
                              void* d_out, int out_size, void* d_ws, size_t ws_size,
                              hipStream_t stream) {
    const float* x1 = (const float*)d_in[0];
    const float* x2 = (const float*)d_in[1];
    const int* mask1 = (const int*)d_in[2];
    const int* mask2 = (const int*)d_in[3];
    char* ws = (char*)d_ws;
    unsigned short* x1h  = (unsigned short*)(ws);
    unsigned short* x2h  = (unsigned short*)(ws + 33554432UL);
    unsigned short* x1l  = (unsigned short*)(ws + 134217728UL);
    unsigned short* x2l  = (unsigned short*)(ws + 167772160UL);
    float* alg           = (float*)(ws + 201326592UL);
    unsigned short* attn12 = (unsigned short*)(ws + 134217728UL);  // reuses x1l
    unsigned short* attn21 = (unsigned short*)(ws + 167772160UL);  // reuses x2l
    float* out1 = (float*)d_out;
    float* out2 = out1 + (size_t)BB * NN * DD;
    float* rp_max = (float*)d_out;            // [32][4][512]
    float* rp_sum = rp_max + 65536;
    float* cp_max = rp_sum + 65536;           // [32][8][512]
    float* cp_sum = cp_max + 131072;

    convert_split<<<2048, 256, 0, stream>>>(x1, x2, x1h, x1l, x2h, x2l);
    gemm_align<<<512, 512, 0, stream>>>(x1h, x1l, x2h, x2l, mask1, mask2, alg,
                                        rp_max, rp_sum, cp_max, cp_sum);
    apply_softmax<<<2048, 256, 0, stream>>>(alg, mask1, mask2,
                                            rp_max, rp_sum, cp_max, cp_sum,
                                            attn12, attn21);
    gemm_pv2<<<2048, 256, 0, stream>>>(attn12, x2h, attn21, x1h, out1, out2);
}

// Round 15
// 365.772 us; speedup vs baseline: 1.0966x; 1.0966x over previous
//
#include <hip/hip_runtime.h>
#include <hip/hip_bf16.h>

#define BB 32
#define NN 512
#define MM 512
#define DD 1024

typedef __attribute__((ext_vector_type(8))) short short8;
typedef __attribute__((ext_vector_type(8))) unsigned short ushort8v;
typedef __attribute__((ext_vector_type(4))) float f32x4;

#define ASYNC_COPY16(g, l) \
    __builtin_amdgcn_global_load_lds((__attribute__((address_space(1))) void*)(g), \
                                     (__attribute__((address_space(3))) void*)(l), 16, 0, 0)

__device__ inline unsigned short f2bf(float f) {
    unsigned int u = __float_as_uint(f);
    u += 0x7fffu + ((u >> 16) & 1u);
    return (unsigned short)(u >> 16);
}

#define SPLIT1(vv, hh, ll) { unsigned short h_ = f2bf(vv); \
    float hf_ = __uint_as_float((unsigned int)h_ << 16); \
    hh = h_; ll = f2bf((vv) - hf_); }

__device__ inline void split8v(f32x4 a0, f32x4 a1, ushort8v& h, ushort8v& l) {
    SPLIT1(a0[0], h[0], l[0]) SPLIT1(a0[1], h[1], l[1])
    SPLIT1(a0[2], h[2], l[2]) SPLIT1(a0[3], h[3], l[3])
    SPLIT1(a1[0], h[4], l[4]) SPLIT1(a1[1], h[5], l[5])
    SPLIT1(a1[2], h[6], l[6]) SPLIT1(a1[3], h[7], l[7])
}

// ---------------------------------------------------------------------------
// K0: streaming split-convert, MLP-restructured (R12 shape). Stores are
// PLAIN (R12's NT stores evicted h/l from L3 and slowed align/pv by ~20us);
// loads are NONTEMPORAL (via ext-vector f32x4, which the builtin accepts):
// x1/x2 are consumed only here, so keep the 128MB of dead fp32 input from
// evicting the h/l outputs that align/pv2 re-read.
// ---------------------------------------------------------------------------
__global__ __launch_bounds__(256) void convert_split(
    const float* __restrict__ x1, const float* __restrict__ x2,
    unsigned short* __restrict__ x1h, unsigned short* __restrict__ x1l,
    unsigned short* __restrict__ x2h, unsigned short* __restrict__ x2l) {
    int tid = blockIdx.x * 256 + threadIdx.x;            // 0..524287
#pragma unroll
    for (int it = 0; it < 4; ++it) {
        size_t c = (size_t)tid + (size_t)it * 524288;    // ushort8 chunk, < 2097152
        const f32x4* p1 = (const f32x4*)x1 + 2 * c;
        const f32x4* p2 = (const f32x4*)x2 + 2 * c;
        f32x4 a0 = __builtin_nontemporal_load(p1);
        f32x4 a1 = __builtin_nontemporal_load(p1 + 1);
        f32x4 b0 = __builtin_nontemporal_load(p2);
        f32x4 b1 = __builtin_nontemporal_load(p2 + 1);
        ushort8v h1, l1, h2, l2;
        split8v(a0, a1, h1, l1);
        split8v(b0, b1, h2, l2);
        *((ushort8v*)x1h + c) = h1;
        *((ushort8v*)x1l + c) = l1;
        *((ushort8v*)x2h + c) = h2;
        *((ushort8v*)x2l + c) = l2;
    }
}

// ---------------------------------------------------------------------------
// K1: align GEMM + fused partial softmax stats. T4 counted-vmcnt K-loop
// (unchanged, R11-passing).
// ---------------------------------------------------------------------------
__global__ __launch_bounds__(512, 4) void gemm_align(
    const unsigned short* __restrict__ x1h, const unsigned short* __restrict__ x1l,
    const unsigned short* __restrict__ x2h, const unsigned short* __restrict__ x2l,
    const int* __restrict__ mask1, const int* __restrict__ mask2,
    float* __restrict__ alg,
    float* __restrict__ rp_max, float* __restrict__ rp_sum,
    float* __restrict__ cp_max, float* __restrict__ cp_sum) {
    __shared__ unsigned short S[2][16384];
    int bid = blockIdx.x;
    int nb = (bid & 7) * 64 + (bid >> 3);    // XCD batch-affinity swizzle
    int b = nb >> 4; int tl = nb & 15;
    int nt = tl >> 2, mt = tl & 3;
    int n0 = nt * 128, m0 = mt * 128;
    int t = threadIdx.x; int w = t >> 6; int l = t & 63;
    int lane16 = l & 15, q = l >> 4, q8 = q * 8;
    int wr = (w >> 2) * 64;
    int wc = (w & 3) * 32;
    f32x4 acc[4][2];
#pragma unroll
    for (int i = 0; i < 4; ++i)
#pragma unroll
        for (int j = 0; j < 2; ++j) acc[i][j] = (f32x4){0.f, 0.f, 0.f, 0.f};
    const unsigned short* gs[4];
    int ls[4];
#pragma unroll
    for (int s = 0; s < 4; ++s) {
        int qq = w * 4 + s;
        int row0 = (qq & 7) * 16;
        const unsigned short* base; int lb;
        if (qq < 8)       { base = x1h + ((size_t)b * 512 + n0) * 1024; lb = 0; }
        else if (qq < 16) { base = x1l + ((size_t)b * 512 + n0) * 1024; lb = 4096; }
        else if (qq < 24) { base = x2h + ((size_t)b * 512 + m0) * 1024; lb = 8192; }
        else              { base = x2l + ((size_t)b * 512 + m0) * 1024; lb = 12288; }
        gs[s] = base + (size_t)(row0 + (l >> 2)) * 1024 + (l & 3) * 8;
        ls[s] = lb + row0 * 32 + l * 8;
    }
#pragma unroll
    for (int s = 0; s < 4; ++s)
        ASYNC_COPY16(gs[s], &S[0][ls[s]]);
    int cur = 0;
    for (int kk = 0; kk < 1024; kk += 32) {
        if (kk + 32 < 1024) {
#pragma unroll
            for (int s = 0; s < 4; ++s)
                ASYNC_COPY16(gs[s] + kk + 32, &S[cur ^ 1][ls[s]]);
            __builtin_amdgcn_sched_barrier(0);
            asm volatile("s_waitcnt vmcnt(4)" ::: "memory");   // tile-t landed, t+1 in flight
        } else {
            asm volatile("s_waitcnt vmcnt(0)" ::: "memory");   // final tile
        }
        __builtin_amdgcn_s_barrier();
        __builtin_amdgcn_sched_barrier(0);
        const unsigned short* Sb = S[cur];
        short8 ah[4], al[4], bh[2], bl[2];
#pragma unroll
        for (int i = 0; i < 4; ++i) {
            int off = (wr + i * 16 + lane16) * 32 + q8;
            ah[i] = *(const short8*)&Sb[off];
            al[i] = *(const short8*)&Sb[4096 + off];
        }
#pragma unroll
        for (int j = 0; j < 2; ++j) {
            int off = (wc + j * 16 + lane16) * 32 + q8;
            bh[j] = *(const short8*)&Sb[8192 + off];
            bl[j] = *(const short8*)&Sb[12288 + off];
        }
#pragma unroll
        for (int i = 0; i < 4; ++i)
#pragma unroll
            for (int j = 0; j < 2; ++j) {
                acc[i][j] = __builtin_amdgcn_mfma_f32_16x16x32_bf16(ah[i], bh[j], acc[i][j], 0, 0, 0);
                acc[i][j] = __builtin_amdgcn_mfma_f32_16x16x32_bf16(ah[i], bl[j], acc[i][j], 0, 0, 0);
                acc[i][j] = __builtin_amdgcn_mfma_f32_16x16x32_bf16(al[i], bh[j], acc[i][j], 0, 0, 0);
            }
        __builtin_amdgcn_sched_barrier(0);
        __builtin_amdgcn_s_barrier();   // all waves done reading buf[cur] before overwrite
        cur ^= 1;
    }
    float* ob = alg + ((size_t)b * 512 + n0 + wr) * 512 + m0 + wc;
    int q4 = q * 4;
#pragma unroll
    for (int i = 0; i < 4; ++i)
#pragma unroll
        for (int j = 0; j < 2; ++j)
#pragma unroll
            for (int r = 0; r < 4; ++r)
                ob[(size_t)(i * 16 + q4 + r) * 512 + j * 16 + lane16] = acc[i][j][r];
    int mk2[2];
#pragma unroll
    for (int j = 0; j < 2; ++j) mk2[j] = mask2[b * 512 + m0 + wc + j * 16 + lane16];
    int mk1r[4][4];
#pragma unroll
    for (int i = 0; i < 4; ++i)
#pragma unroll
        for (int r = 0; r < 4; ++r) mk1r[i][r] = mask1[b * 512 + n0 + wr + i * 16 + q4 + r];
#pragma unroll
    for (int j = 0; j < 2; ++j) {
        float cm = -3.0e38f;
#pragma unroll
        for (int i = 0; i < 4; ++i)
#pragma unroll
            for (int r = 0; r < 4; ++r)
                if (mk1r[i][r]) cm = fmaxf(cm, acc[i][j][r]);
        cm = fmaxf(cm, __shfl_xor(cm, 16));
        cm = fmaxf(cm, __shfl_xor(cm, 32));
        float cs = 0.f;
#pragma unroll
        for (int i = 0; i < 4; ++i)
#pragma unroll
            for (int r = 0; r < 4; ++r)
                cs += mk1r[i][r] ? __expf(acc[i][j][r] - cm) : 0.f;
        cs += __shfl_xor(cs, 16);
        cs += __shfl_xor(cs, 32);
        if (q == 0) {
            size_t o = ((size_t)b * 8 + nt * 2 + (w >> 2)) * 512 + m0 + wc + j * 16 + lane16;
            cp_max[o] = cm;
            cp_sum[o] = cs;
        }
    }
    float* rmS = (float*)&S[0][0];
    float* rsS = rmS + 512;
#pragma unroll
    for (int i = 0; i < 4; ++i)
#pragma unroll
        for (int r = 0; r < 4; ++r) {
            float v0 = acc[i][0][r], v1 = acc[i][1][r];
            float rm = fmaxf(mk2[0] ? v0 : -3.0e38f, mk2[1] ? v1 : -3.0e38f);
            rm = fmaxf(rm, __shfl_xor(rm, 1));
            rm = fmaxf(rm, __shfl_xor(rm, 2));
            rm = fmaxf(rm, __shfl_xor(rm, 4));
            rm = fmaxf(rm, __shfl_xor(rm, 8));
            float rs = (mk2[0] ? __expf(v0 - rm) : 0.f) + (mk2[1] ? __expf(v1 - rm) : 0.f);
            rs += __shfl_xor(rs, 1);
            rs += __shfl_xor(rs, 2);
            rs += __shfl_xor(rs, 4);
            rs += __shfl_xor(rs, 8);
            if (lane16 == 0) {
                int row = i * 16 + q4 + r;
                rmS[w * 64 + row] = rm;
                rsS[w * 64 + row] = rs;
            }
        }
    __syncthreads();
    if (t < 128) {
        int grp = t >> 6, rloc = t & 63;
        float M = -3.0e38f;
#pragma unroll
        for (int ww = 0; ww < 4; ++ww) M = fmaxf(M, rmS[(grp * 4 + ww) * 64 + rloc]);
        float Ssum = 0.f;
#pragma unroll
        for (int ww = 0; ww < 4; ++ww)
            Ssum += rsS[(grp * 4 + ww) * 64 + rloc] * __expf(rmS[(grp * 4 + ww) * 64 + rloc] - M);
        size_t o = ((size_t)b * 4 + mt) * 512 + n0 + t;
        rp_max[o] = M;
        rp_sum[o] = Ssum;
    }
}

// ---------------------------------------------------------------------------
// K3': apply softmax with combine_stats fused (unchanged, R11-passing).
// ---------------------------------------------------------------------------
__global__ __launch_bounds__(256) void apply_softmax(
    const float* __restrict__ alg, const int* __restrict__ mask1,
    const int* __restrict__ mask2,
    const float* __restrict__ rp_max, const float* __restrict__ rp_sum,
    const float* __restrict__ cp_max, const float* __restrict__ cp_sum,
    unsigned short* __restrict__ attn12, unsigned short* __restrict__ attn21) {
    int bid = blockIdx.x; int b = bid >> 6; int rem = bid & 63;
    int m0 = (rem >> 3) * 64, n0 = (rem & 7) * 64;
    int t = threadIdx.x;
    __shared__ float lds[64 * 65];
    __shared__ float st[4][64];   // rowmax, rowinv, colmax, colinv (block-local)
    if (t < 64) {
        int n = n0 + t;
        float M = -3.0e38f;
#pragma unroll
        for (int tt = 0; tt < 4; ++tt) M = fmaxf(M, rp_max[((size_t)b * 4 + tt) * 512 + n]);
        float Ssum = 0.f;
#pragma unroll
        for (int tt = 0; tt < 4; ++tt) {
            size_t o = ((size_t)b * 4 + tt) * 512 + n;
            Ssum += rp_sum[o] * __expf(rp_max[o] - M);
        }
        st[0][t] = M; st[1][t] = 1.0f / Ssum;
    } else if (t < 128) {
        int m = m0 + (t - 64);
        float M = -3.0e38f;
#pragma unroll
        for (int tt = 0; tt < 8; ++tt) M = fmaxf(M, cp_max[((size_t)b * 8 + tt) * 512 + m]);
        float Ssum = 0.f;
#pragma unroll
        for (int tt = 0; tt < 8; ++tt) {
            size_t o = ((size_t)b * 8 + tt) * 512 + m;
            Ssum += cp_sum[o] * __expf(cp_max[o] - M);
        }
        st[2][t - 64] = M; st[3][t - 64] = 1.0f / Ssum;
    }
    __syncthreads();
    int jj = t & 63; int ii = t >> 6;
    int mk2 = mask2[b * 512 + m0 + jj];
    unsigned short e12[16];
#pragma unroll
    for (int p = 0; p < 16; ++p) {
        int n = ii + p * 4;
        float v = alg[((size_t)b * 512 + n0 + n) * 512 + m0 + jj];
        lds[n * 65 + jj] = v;
        e12[p] = mk2 ? f2bf(__expf(v - st[0][n]) * st[1][n]) : (unsigned short)0;
    }
    __syncthreads();
#pragma unroll
    for (int p = 0; p < 16; ++p) {
        int n = ii + p * 4;
        attn12[((size_t)b * 512 + n0 + n) * 512 + m0 + jj] = e12[p];
    }
    int mk1 = mask1[b * 512 + n0 + jj];
#pragma unroll
    for (int p = 0; p < 16; ++p) {
        int mm = ii + p * 4;
        float v = lds[jj * 65 + mm];
        unsigned short pv = mk1 ? f2bf(__expf(v - st[2][mm]) * st[3][mm]) : (unsigned short)0;
        attn21[((size_t)b * 512 + m0 + mm) * 512 + n0 + jj] = pv;
    }
}

// ---------------------------------------------------------------------------
// K4: merged PV GEMM, T4 counted-vmcnt loop (unchanged, R11-passing).
// ---------------------------------------------------------------------------
__global__ __launch_bounds__(256) void gemm_pv2(
    const unsigned short* __restrict__ attn12, const unsigned short* __restrict__ x2h,
    const unsigned short* __restrict__ attn21, const unsigned short* __restrict__ x1h,
    float* __restrict__ out1, float* __restrict__ out2) {
    __shared__ unsigned short SA[2][4096];       // [128n][32m] bf16
    __shared__ unsigned int   SB[2][32 * 65];    // [32m][130 u16] padded
    int bid0 = blockIdx.x;
    const unsigned short* P; const unsigned short* V; float* out;
    if (bid0 < 1024) { P = attn12; V = x2h; out = out1; }
    else             { P = attn21; V = x1h; out = out2; }
    int bid = bid0 & 1023;
    int nb = (bid & 7) * 128 + (bid >> 3);  // XCD batch-affinity swizzle
    int b = nb >> 5; int rem = nb & 31;
    int n0 = (rem >> 3) * 128, d0 = (rem & 7) * 128;
    int t = threadIdx.x; int w = t >> 6; int l = t & 63;
    int lane16 = l & 15, q = l >> 4, q8 = q * 8;
    int wr = (w >> 1) * 64, wc = (w & 1) * 64;
    f32x4 acc[4][4];
#pragma unroll
    for (int i = 0; i < 4; ++i)
#pragma unroll
        for (int j = 0; j < 4; ++j) acc[i][j] = (f32x4){0.f, 0.f, 0.f, 0.f};
    const unsigned short* gA = P + ((size_t)b * 512 + n0) * 512;
    const unsigned short* gsA[2];
    int ldsa[2];
#pragma unroll
    for (int s = 0; s < 2; ++s) {
        int a = w * 2 + s;
        gsA[s] = gA + (size_t)(a * 16 + (l >> 2)) * 512 + (l & 3) * 8;
        ldsa[s] = a * 512 + l * 8;
    }
    int dch = l & 15;
    int mloc[2]; mloc[0] = w * 4 + q; mloc[1] = mloc[0] + 16;
    const unsigned short* gB0[2];
#pragma unroll
    for (int s = 0; s < 2; ++s)
        gB0[s] = V + (size_t)b * 524288 + (size_t)mloc[s] * 1024 + d0 + dch * 8;
    union U8 { short8 s; unsigned int u[4]; };
    U8 bv[2];
#pragma unroll
    for (int s = 0; s < 2; ++s) bv[s].s = *(const short8*)gB0[s];
#pragma unroll
    for (int s = 0; s < 2; ++s)
        ASYNC_COPY16(gsA[s], &SA[0][ldsa[s]]);
#pragma unroll
    for (int s = 0; s < 2; ++s)
#pragma unroll
        for (int c = 0; c < 4; ++c)
            SB[0][mloc[s] * 65 + dch * 4 + c] = bv[s].u[c];
    __syncthreads();
    int cur = 0;
    for (int kk = 0; kk < 512; kk += 32) {
        int more = (kk + 32 < 512);
        if (more) {
#pragma unroll
            for (int s = 0; s < 2; ++s) bv[s].s = *(const short8*)(gB0[s] + (size_t)(kk + 32) * 1024);
            __builtin_amdgcn_sched_barrier(0);   // keep bv-loads older than A-DMA
#pragma unroll
            for (int s = 0; s < 2; ++s)
                ASYNC_COPY16(gsA[s] + kk + 32, &SA[cur ^ 1][ldsa[s]]);
            __builtin_amdgcn_sched_barrier(0);
            asm volatile("s_waitcnt vmcnt(4)" ::: "memory");   // A(t) landed; {bv,A}(t+1) in flight
        } else {
            asm volatile("s_waitcnt vmcnt(0)" ::: "memory");
        }
        __builtin_amdgcn_s_barrier();
        __builtin_amdgcn_sched_barrier(0);
        short8 af[4];
#pragma unroll
        for (int i = 0; i < 4; ++i)
            af[i] = *(const short8*)&SA[cur][(wr + i * 16 + lane16) * 32 + q8];
        const unsigned short* Bs = (const unsigned short*)SB[cur];
        short8 bf[4];
#pragma unroll
        for (int j = 0; j < 4; ++j) {
            int col = wc + j * 16 + lane16;
#pragma unroll
            for (int e = 0; e < 8; ++e)
                bf[j][e] = (short)Bs[(q8 + e) * 130 + col];
        }
#pragma unroll
        for (int i = 0; i < 4; ++i)
#pragma unroll
            for (int j = 0; j < 4; ++j)
                acc[i][j] = __builtin_amdgcn_mfma_f32_16x16x32_bf16(af[i], bf[j], acc[i][j], 0, 0, 0);
        if (more) {
#pragma unroll
            for (int s = 0; s < 2; ++s)
#pragma unroll
                for (int c = 0; c < 4; ++c)
                    SB[cur ^ 1][mloc[s] * 65 + dch * 4 + c] = bv[s].u[c];
        }
        asm volatile("s_waitcnt lgkmcnt(0)" ::: "memory");   // SB writes visible
        __builtin_amdgcn_sched_barrier(0);
        __builtin_amdgcn_s_barrier();
        cur ^= 1;
    }
    int q4 = q * 4;
#pragma unroll
    for (int i = 0; i < 4; ++i)
#pragma unroll
        for (int j = 0; j < 4; ++j)
#pragma unroll
            for (int r = 0; r < 4; ++r) {
                int rr = n0 + wr + i * 16 + q4 + r;
                int dd = d0 + wc + j * 16 + lane16;
                out[((size_t)b * 512 + rr) * DD + dd] = acc[i][j][r];
            }
}

// ---------------------------------------------------------------------------
// ws layout (224MB): x1h 0 | x2h 32M | x1l 128M | x2l 160M | alg 192M.
// attn12 @128M (reuses x1l), attn21 @160M (reuses x2l). Partial stats in
// d_out scratch (dead before gemm_pv2 writes it). 4 launches total.
// ---------------------------------------------------------------------------
extern "C" void kernel_launch(void* const* d_in, const int* in_sizes, int n_in,
                              void* d_out, int out_size, void* d_ws, size_t ws_size,
                              hipStream_t stream) {
    const float* x1 = (const float*)d_in[0];
    const float* x2 = (const float*)d_in[1];
    const int* mask1 = (const int*)d_in[2];
    const int* mask2 = (const int*)d_in[3];
    char* ws = (char*)d_ws;
    unsigned short* x1h  = (unsigned short*)(ws);
    unsigned short* x2h  = (unsigned short*)(ws + 33554432UL);
    unsigned short* x1l  = (unsigned short*)(ws + 134217728UL);
    unsigned short* x2l  = (unsigned short*)(ws + 167772160UL);
    float* alg           = (float*)(ws + 201326592UL);
    unsigned short* attn12 = (unsigned short*)(ws + 134217728UL);  // reuses x1l
    unsigned short* attn21 = (unsigned short*)(ws + 167772160UL);  // reuses x2l
    float* out1 = (float*)d_out;
    float* out2 = out1 + (size_t)BB * NN * DD;
    float* rp_max = (float*)d_out;            // [32][4][512]
    float* rp_sum = rp_max + 65536;
    float* cp_max = rp_sum + 65536;           // [32][8][512]
    float* cp_sum = cp_max + 131072;

    convert_split<<<2048, 256, 0, stream>>>(x1, x2, x1h, x1l, x2h, x2l);
    gemm_align<<<512, 512, 0, stream>>>(x1h, x1l, x2h, x2l, mask1, mask2, alg,
                                        rp_max, rp_sum, cp_max, cp_sum);
    apply_softmax<<<2048, 256, 0, stream>>>(alg, mask1, mask2,
                                            rp_max, rp_sum, cp_max, cp_sum,
                                            attn12, attn21);
    gemm_pv2<<<2048, 256, 0, stream>>>(attn12, x2h, attn21, x1h, out1, out2);
}